// Round 3
// baseline (3643.003 us; speedup 1.0000x reference)
//
#include <hip/hip_runtime.h>
#include <cfloat>

#define NRW 32768
#define KC 4096
#define CD 256
#define HW 1024
#define XPAD 260

// ---------- se[k] = np.sum(cb[k]**2) : numpy pairwise (128+128, scalar 8-acc) ----------
// one 8-lane group per code; shuffle tree reproduces ((r0+r1)+(r2+r3))+((r4+r5)+(r6+r7))
__global__ __launch_bounds__(256) void vq_se(const float* __restrict__ cb,
                                             float* __restrict__ se) {
#pragma clang fp contract(off)
  const int tid = threadIdx.x;
  const int g = tid >> 3;
  const int j = tid & 7;
  const int code = blockIdx.x * 32 + g;
  const float* e = cb + (size_t)code * CD;
  float half[2];
#pragma unroll
  for (int h = 0; h < 2; ++h) {
    const float* a = e + h * 128;
    float v = a[j];
    float r = v * v;
#pragma unroll
    for (int i = 1; i < 16; ++i) {
      float w = a[8 * i + j];
      float w2 = w * w;
      r = r + w2;
    }
    float l1 = r + __shfl_down(r, 1, 8);
    float l2 = l1 + __shfl_down(l1, 2, 8);
    float l3 = l2 + __shfl_down(l2, 4, 8);
    half[h] = l3;
  }
  if (j == 0) se[code] = half[0] + half[1];
}

// ---------- main: bit-exact np fp32 dist + first-index argmin ----------
__global__ __launch_bounds__(256) void vq_dist(const float* __restrict__ x,
                                               const float* __restrict__ cb,
                                               const float* __restrict__ se,
                                               float* __restrict__ outids) {
#pragma clang fp contract(off)
  __shared__ float xs[32][XPAD];
  __shared__ float es[8][XPAD];
  __shared__ float sxs[32];
  __shared__ float rmin[32][8];
  __shared__ int   rk[32][8];

  const int tid = threadIdx.x;
  const int b   = blockIdx.x >> 5;
  const int hw0 = (blockIdx.x & 31) << 5;
  const float* xb = x + (size_t)b * CD * HW + hw0;

  // stage 32 x-rows (coalesced global reads)
  for (int idx = tid; idx < 32 * CD; idx += 256) {
    const int c = idx >> 5, r = idx & 31;
    xs[r][c] = xb[(size_t)c * HW + r];
  }
  __syncthreads();

  // sx[n] = np.sum(xf[n]**2): numpy pairwise, one 8-lane group per row
  {
    const int r = tid >> 3, j = tid & 7;
    float half[2];
#pragma unroll
    for (int h = 0; h < 2; ++h) {
      const float* a = &xs[r][h * 128];
      float v = a[j];
      float s = v * v;
#pragma unroll
      for (int i = 1; i < 16; ++i) {
        float w = a[8 * i + j];
        float w2 = w * w;
        s = s + w2;
      }
      float l1 = s + __shfl_down(s, 1, 8);
      float l2 = l1 + __shfl_down(l1, 2, 8);
      float l3 = l2 + __shfl_down(l2, 4, 8);
      half[h] = l3;
    }
    if (j == 0) sxs[r] = half[0] + half[1];
  }
  __syncthreads();

  const int row = tid >> 3, ks = tid & 7;
  const float sxv = sxs[row];
  const float4* xv4 = (const float4*)&xs[row][0];

  float m1 = FLT_MAX;
  int   mi = 0;

  for (int k0 = 0; k0 < KC; k0 += 8) {
    __syncthreads();
#pragma unroll
    for (int i = 0; i < 8; ++i) es[i][tid] = cb[(size_t)(k0 + i) * CD + tid];
    __syncthreads();

    // np.einsum fp32 (baseline-SIMD SSE path): vstep=4 lanes, blocks of 16,
    // within-block chain j=3..0, mul & add separately rounded (NO fma)
    const float4* ev4 = (const float4*)&es[ks][0];
    float a0 = 0.f, a1 = 0.f, a2 = 0.f, a3 = 0.f;
#pragma unroll
    for (int B = 0; B < 16; ++B) {
#pragma unroll
      for (int j = 3; j >= 0; --j) {
        const float4 xv = xv4[4 * B + j];
        const float4 ev = ev4[4 * B + j];
        float p0 = xv.x * ev.x; a0 = a0 + p0;
        float p1 = xv.y * ev.y; a1 = a1 + p1;
        float p2 = xv.z * ev.z; a2 = a2 + p2;
        float p3 = xv.w * ev.w; a3 = a3 + p3;
      }
    }
    // SSE3 horizontal tree: (v0+v1) + (v2+v3)
    const float dot = (a0 + a1) + (a2 + a3);
    const float sq  = se[k0 + ks] + sxv;   // se ⊕ sx (single fp32 add)
    const float td  = 2.0f * dot;          // exact
    const float dist = sq - td;            // single fp32 subtract

    const int k = k0 + ks;
    if (dist < m1) { m1 = dist; mi = k; }  // per-thread k ascending -> first-min kept
  }

  rmin[row][ks] = m1;
  rk[row][ks]   = mi;
  __syncthreads();

  if (tid < 32) {
    float best = rmin[tid][0];
    int   bi   = rk[tid][0];
    for (int s = 1; s < 8; ++s) {
      const float v = rmin[tid][s];
      const int  ix = rk[tid][s];
      if (v < best || (v == best && ix < bi)) { best = v; bi = ix; }
    }
    outids[b * HW + hw0 + tid] = (float)bi;
  }
}

// ---------- emb gather ----------
__global__ __launch_bounds__(256) void vq_emb_out(const float* __restrict__ outids,
                                                  const float* __restrict__ cb,
                                                  float* __restrict__ out) {
  const int bx = blockIdx.x;
  const int b = bx >> 10;
  const int rem = bx & 1023;
  const int c = rem >> 2;
  const int q = rem & 3;
  const int hw = q * 256 + threadIdx.x;
  const int id = (int)outids[b * HW + hw];
  out[((size_t)(b * CD + c)) * HW + hw] = cb[(size_t)id * CD + c];
}

extern "C" void kernel_launch(void* const* d_in, const int* in_sizes, int n_in,
                              void* d_out, int out_size, void* d_ws, size_t ws_size,
                              hipStream_t stream) {
  const float* x  = (const float*)d_in[0];   // (32,256,32,32) f32
  const float* cb = (const float*)d_in[1];   // (4096,256) f32
  float* out = (float*)d_out;                // [0..32767]=ids, [32768..]=emb (B,C,H,W)

  float* se = (float*)d_ws;                  // 16 KB

  vq_se<<<128, 256, 0, stream>>>(cb, se);
  vq_dist<<<1024, 256, 0, stream>>>(x, cb, se, out);
  vq_emb_out<<<32768, 256, 0, stream>>>(out, cb, out + NRW);
}